// Round 1
// baseline (182.265 us; speedup 1.0000x reference)
//
#include <hip/hip_runtime.h>
#include <hip/hip_bf16.h>

typedef short short8 __attribute__((ext_vector_type(8)));
typedef float f32x4  __attribute__((ext_vector_type(4)));
typedef float f32x16 __attribute__((ext_vector_type(16)));

__device__ __forceinline__ unsigned short f2bf(float f) {
  unsigned u = __builtin_bit_cast(unsigned, f);
  u += 0x7fffu + ((u >> 16) & 1u);           // round-to-nearest-even
  return (unsigned short)(u >> 16);
}

// C[m][n] = sum_k A[m][k] * B[n][k], K=256 fixed, bf16 output (raw bits in short)
__global__ __launch_bounds__(256) void proj_kernel(const float* __restrict__ A,
                                                   const float* __restrict__ Bm,
                                                   short* __restrict__ C, int N) {
  __shared__ short At[128][40];
  __shared__ short Bt[128][40];
  const int t = threadIdx.x;
  const int w = t >> 6, l = t & 63;
  const int m0 = blockIdx.x * 128, n0 = blockIdx.y * 128;
  const int wr = (w >> 1) * 64, wc = (w & 1) * 64;
  f32x4 acc[4][4] = {};
  for (int k0 = 0; k0 < 256; k0 += 32) {
    __syncthreads();
    #pragma unroll
    for (int rep = 0; rep < 4; ++rep) {
      int row = (t >> 3) + rep * 32;
      int c4  = (t & 7) * 4;
      float4 va = *(const float4*)(A + (size_t)(m0 + row) * 256 + k0 + c4);
      unsigned long long pa = (unsigned long long)f2bf(va.x) |
                              ((unsigned long long)f2bf(va.y) << 16) |
                              ((unsigned long long)f2bf(va.z) << 32) |
                              ((unsigned long long)f2bf(va.w) << 48);
      *(unsigned long long*)&At[row][c4] = pa;
      float4 vb = *(const float4*)(Bm + (size_t)(n0 + row) * 256 + k0 + c4);
      unsigned long long pb = (unsigned long long)f2bf(vb.x) |
                              ((unsigned long long)f2bf(vb.y) << 16) |
                              ((unsigned long long)f2bf(vb.z) << 32) |
                              ((unsigned long long)f2bf(vb.w) << 48);
      *(unsigned long long*)&Bt[row][c4] = pb;
    }
    __syncthreads();
    short8 af[4], bf[4];
    #pragma unroll
    for (int i = 0; i < 4; ++i) {
      af[i] = *(const short8*)&At[wr + i * 16 + (l & 15)][(l >> 4) * 8];
      bf[i] = *(const short8*)&Bt[wc + i * 16 + (l & 15)][(l >> 4) * 8];
    }
    #pragma unroll
    for (int i = 0; i < 4; ++i)
      #pragma unroll
      for (int j = 0; j < 4; ++j)
        acc[i][j] = __builtin_amdgcn_mfma_f32_16x16x32_bf16(af[i], bf[j], acc[i][j], 0, 0, 0);
  }
  #pragma unroll
  for (int i = 0; i < 4; ++i)
    #pragma unroll
    for (int j = 0; j < 4; ++j)
      #pragma unroll
      for (int r = 0; r < 4; ++r) {
        int row = m0 + wr + i * 16 + (l >> 4) * 4 + r;
        int col = n0 + wc + j * 16 + (l & 15);
        C[(size_t)row * N + col] = (short)f2bf(acc[i][j][r]);
      }
}

// Flash attention: Q,K row-major bf16 [16384][256]; VT bf16 [256][16384]; O fp32 [16384][256]
// grid (64, 8); block 256 = 4 waves; each wave: 32 q-rows x strided quarter of KV.
__global__ __launch_bounds__(256, 2) void attn_kernel(const short* __restrict__ Q,
                                                      const short* __restrict__ K,
                                                      const short* __restrict__ VT,
                                                      float* __restrict__ O) {
  __shared__ short P_lds[4][32][40];
  __shared__ float m_sh[4][32], l_sh[4][32], a_sh[4][32];
  __shared__ float ot_sh[4][32][33];
  const int t = threadIdx.x;
  const int w = t >> 6, l = t & 63;
  const int lane31 = l & 31, grp = l >> 5;
  const int b = blockIdx.y, q0 = blockIdx.x * 32;
  const size_t bS = (size_t)b * 2048;

  // Q as b-frags (B = Q^T), held in registers, reused across all 16 KV tiles
  short8 qf[16];
  const short* qrow = Q + (bS + q0 + lane31) * 256 + grp * 8;
  #pragma unroll
  for (int kf = 0; kf < 16; ++kf) qf[kf] = *(const short8*)(qrow + kf * 16);

  f32x16 ot[8] = {};
  float m = -1e30f, lsum = 0.f;

  for (int it = 0; it < 16; ++it) {
    const int kv0 = (w + it * 4) * 32;
    // S^T = K * Q^T  (two interleaved accumulation chains)
    f32x16 st0 = {}, st1 = {};
    const short* krow = K + (bS + kv0 + lane31) * 256 + grp * 8;
    #pragma unroll
    for (int kf = 0; kf < 16; kf += 2) {
      short8 a0 = *(const short8*)(krow + kf * 16);
      short8 a1 = *(const short8*)(krow + kf * 16 + 16);
      st0 = __builtin_amdgcn_mfma_f32_32x32x16_bf16(a0, qf[kf], st0, 0, 0, 0);
      st1 = __builtin_amdgcn_mfma_f32_32x32x16_bf16(a1, qf[kf + 1], st1, 0, 0, 0);
    }
    f32x16 st = st0 + st1;

    // online softmax (lane-local q-row: col = l&31; rows of S^T = kv live in regs + grp)
    float tmax = st[0];
    #pragma unroll
    for (int r = 1; r < 16; ++r) tmax = fmaxf(tmax, st[r]);
    tmax = fmaxf(tmax, __shfl_xor(tmax, 32, 64));
    float mnew = fmaxf(m, tmax);
    float corr = __expf(m - mnew);
    float p[16];
    float psum = 0.f;
    #pragma unroll
    for (int r = 0; r < 16; ++r) { p[r] = __expf(st[r] - mnew); psum += p[r]; }
    psum += __shfl_xor(psum, 32, 64);
    lsum = lsum * corr + psum;
    m = mnew;
    #pragma unroll
    for (int db = 0; db < 8; ++db) ot[db] *= corr;

    // P -> per-wave LDS tile [32 q][32 kv] (row stride 40 bf16 = 80B, 16B-aligned)
    #pragma unroll
    for (int rp = 0; rp < 4; ++rp) {
      unsigned long long pk = (unsigned long long)f2bf(p[rp * 4]) |
                              ((unsigned long long)f2bf(p[rp * 4 + 1]) << 16) |
                              ((unsigned long long)f2bf(p[rp * 4 + 2]) << 32) |
                              ((unsigned long long)f2bf(p[rp * 4 + 3]) << 48);
      *(unsigned long long*)&P_lds[w][lane31][rp * 8 + grp * 4] = pk;
    }

    // O^T += V^T * P^T
    const short* vbase = VT + bS + kv0 + grp * 8;
    #pragma unroll
    for (int kf2 = 0; kf2 < 2; ++kf2) {
      short8 pb = *(const short8*)&P_lds[w][lane31][kf2 * 16 + grp * 8];
      #pragma unroll
      for (int db = 0; db < 8; ++db) {
        short8 vf = *(const short8*)(vbase + (size_t)(db * 32 + lane31) * 16384 + kf2 * 16);
        ot[db] = __builtin_amdgcn_mfma_f32_32x32x16_bf16(vf, pb, ot[db], 0, 0, 0);
      }
    }
  }

  // cross-wave merge (4 KV-stripe partials per q-row)
  if (l < 32) { m_sh[w][lane31] = m; l_sh[w][lane31] = lsum; }
  __syncthreads();
  if (t < 128) {
    int c = t >> 5, q = t & 31;
    float ms = fmaxf(fmaxf(m_sh[0][q], m_sh[1][q]), fmaxf(m_sh[2][q], m_sh[3][q]));
    float L = 0.f;
    #pragma unroll
    for (int i = 0; i < 4; ++i) L += l_sh[i][q] * __expf(m_sh[i][q] - ms);
    a_sh[c][q] = __expf(m_sh[c][q] - ms) / L;
  }
  #pragma unroll
  for (int db = 0; db < 8; ++db) {
    __syncthreads();
    #pragma unroll
    for (int r = 0; r < 16; ++r)
      ot_sh[w][(r & 3) + 8 * (r >> 2) + 4 * grp][lane31] = ot[db][r];
    __syncthreads();
    int dloc = t & 31, qq = t >> 5;
    #pragma unroll
    for (int qi = 0; qi < 4; ++qi) {
      int q = qq + 8 * qi;
      float val = a_sh[0][q] * ot_sh[0][dloc][q] + a_sh[1][q] * ot_sh[1][dloc][q] +
                  a_sh[2][q] * ot_sh[2][dloc][q] + a_sh[3][q] * ot_sh[3][dloc][q];
      O[(bS + q0 + q) * 256 + db * 32 + dloc] = val;
    }
  }
}

extern "C" void kernel_launch(void* const* d_in, const int* in_sizes, int n_in,
                              void* d_out, int out_size, void* d_ws, size_t ws_size,
                              hipStream_t stream) {
  (void)in_sizes; (void)n_in; (void)out_size; (void)ws_size;
  const float* query  = (const float*)d_in[0];
  const float* key_in = (const float*)d_in[1];
  const float* value  = (const float*)d_in[2];
  const float* Wq     = (const float*)d_in[3];
  const float* Wk     = (const float*)d_in[4];
  const float* Wv     = (const float*)d_in[5];
  float* out = (float*)d_out;

  short* q_ws = (short*)d_ws;                 // [16384][256] bf16
  short* k_ws = q_ws + (size_t)16384 * 256;   // [16384][256] bf16
  short* vT   = k_ws + (size_t)16384 * 256;   // [256][16384] bf16

  dim3 gqk(128, 2), gv(2, 128), ga(64, 8);
  proj_kernel<<<gqk, 256, 0, stream>>>(query,  Wq,    q_ws, 256);
  proj_kernel<<<gqk, 256, 0, stream>>>(key_in, Wk,    k_ws, 256);
  proj_kernel<<<gv,  256, 0, stream>>>(Wv,     value, vT,   16384);
  attn_kernel<<<ga, 256, 0, stream>>>(q_ws, k_ws, vT, out);
}

// Round 2
// 167.115 us; speedup vs baseline: 1.0907x; 1.0907x over previous
//
#include <hip/hip_runtime.h>
#include <hip/hip_bf16.h>

typedef short short8 __attribute__((ext_vector_type(8)));
typedef float f32x4  __attribute__((ext_vector_type(4)));
typedef float f32x16 __attribute__((ext_vector_type(16)));

__device__ __forceinline__ unsigned short f2bf(float f) {
  unsigned u = __builtin_bit_cast(unsigned, f);
  u += 0x7fffu + ((u >> 16) & 1u);           // round-to-nearest-even
  return (unsigned short)(u >> 16);
}

// C[m][n] = sum_k A[m][k]*B[n][k], K=256. Output written in MFMA-fragment-packed
// order so the attention kernel's fragment loads are coalesced.
// MODE 0 (Q/K): m=seq (16384), n=d (256). Packed A-frag/B-frag for 32x32x16:
//   KP[(((b*64+T)*16+kf)*64 + grp*32 + seq&31)*8 + (d&7)]
// MODE 1 (V):   m=d (256), n=seq (16384). Packed PV A-frag:
//   VP[((((b*64+T)*2+kf2)*8+db)*64 + grp*32 + d&31)*8 + (seq&7)]
template <int MODE>
__global__ __launch_bounds__(256) void proj_kernel(const float* __restrict__ A,
                                                   const float* __restrict__ Bm,
                                                   short* __restrict__ C) {
  __shared__ short At[128][40];
  __shared__ short Bt[128][40];
  const int t = threadIdx.x;
  const int w = t >> 6, l = t & 63;
  const int m0 = blockIdx.x * 128, n0 = blockIdx.y * 128;
  const int wr = (w >> 1) * 64, wc = (w & 1) * 64;
  f32x4 acc[4][4] = {};
  for (int k0 = 0; k0 < 256; k0 += 32) {
    __syncthreads();
    #pragma unroll
    for (int rep = 0; rep < 4; ++rep) {
      int row = (t >> 3) + rep * 32;
      int c4  = (t & 7) * 4;
      float4 va = *(const float4*)(A + (size_t)(m0 + row) * 256 + k0 + c4);
      unsigned long long pa = (unsigned long long)f2bf(va.x) |
                              ((unsigned long long)f2bf(va.y) << 16) |
                              ((unsigned long long)f2bf(va.z) << 32) |
                              ((unsigned long long)f2bf(va.w) << 48);
      *(unsigned long long*)&At[row][c4] = pa;
      float4 vb = *(const float4*)(Bm + (size_t)(n0 + row) * 256 + k0 + c4);
      unsigned long long pb = (unsigned long long)f2bf(vb.x) |
                              ((unsigned long long)f2bf(vb.y) << 16) |
                              ((unsigned long long)f2bf(vb.z) << 32) |
                              ((unsigned long long)f2bf(vb.w) << 48);
      *(unsigned long long*)&Bt[row][c4] = pb;
    }
    __syncthreads();
    short8 af[4], bf[4];
    #pragma unroll
    for (int i = 0; i < 4; ++i) {
      af[i] = *(const short8*)&At[wr + i * 16 + (l & 15)][(l >> 4) * 8];
      bf[i] = *(const short8*)&Bt[wc + i * 16 + (l & 15)][(l >> 4) * 8];
    }
    #pragma unroll
    for (int i = 0; i < 4; ++i)
      #pragma unroll
      for (int j = 0; j < 4; ++j)
        acc[i][j] = __builtin_amdgcn_mfma_f32_16x16x32_bf16(af[i], bf[j], acc[i][j], 0, 0, 0);
  }
  #pragma unroll
  for (int i = 0; i < 4; ++i)
    #pragma unroll
    for (int j = 0; j < 4; ++j)
      #pragma unroll
      for (int r = 0; r < 4; ++r) {
        int row = m0 + wr + i * 16 + (l >> 4) * 4 + r;
        int col = n0 + wc + j * 16 + (l & 15);
        size_t idx;
        if (MODE == 0) {
          int b = row >> 11, s = row & 2047;
          int T = s >> 5, ln = s & 31;
          int kf = col >> 4, g = (col >> 3) & 1, jj = col & 7;
          idx = (((size_t)(b * 64 + T) * 16 + kf) * 64 + g * 32 + ln) * 8 + jj;
        } else {
          int b = col >> 11, s = col & 2047;
          int T = s >> 5, k2 = (s >> 4) & 1, g = (s >> 3) & 1, jj = s & 7;
          int db = row >> 5, ln = row & 31;
          idx = ((((size_t)(b * 64 + T) * 2 + k2) * 8 + db) * 64 + g * 32 + ln) * 8 + jj;
        }
        C[idx] = (short)f2bf(acc[i][j][r]);
      }
}

// Flash attention on fragment-packed Q/K/V. grid (64,8); 4 waves/block;
// each wave: 32 q-rows x strided quarter of KV; cross-wave merge at end.
__global__ __launch_bounds__(256, 2) void attn_kernel(const short* __restrict__ QP,
                                                      const short* __restrict__ KP,
                                                      const short* __restrict__ VP,
                                                      float* __restrict__ O) {
  __shared__ short P_lds[4][32][40];
  __shared__ float m_sh[4][32], l_sh[4][32], a_sh[4][32];
  __shared__ float ot_sh[4][32][33];
  const int t = threadIdx.x;
  const int w = t >> 6, l = t & 63;
  const int lane31 = l & 31, grp = l >> 5;
  const int b = blockIdx.y, q0 = blockIdx.x * 32;
  const size_t bS = (size_t)b * 2048;

  // Q B-frags (coalesced: lane l reads its own 16B chunk)
  short8 qf[16];
  const short* qbase = QP + ((size_t)(b * 64 + (q0 >> 5)) * 16) * 512 + l * 8;
  #pragma unroll
  for (int kf = 0; kf < 16; ++kf) qf[kf] = *(const short8*)(qbase + kf * 512);

  f32x16 ot[8] = {};
  float m = -1e30f, lsum = 0.f;

  for (int it = 0; it < 16; ++it) {
    const int T = w + it * 4;
    // S^T = K * Q^T
    f32x16 st0 = {}, st1 = {};
    const short* kbase = KP + ((size_t)(b * 64 + T) * 16) * 512 + l * 8;
    #pragma unroll
    for (int kf = 0; kf < 16; kf += 2) {
      short8 a0 = *(const short8*)(kbase + kf * 512);
      short8 a1 = *(const short8*)(kbase + kf * 512 + 512);
      st0 = __builtin_amdgcn_mfma_f32_32x32x16_bf16(a0, qf[kf], st0, 0, 0, 0);
      st1 = __builtin_amdgcn_mfma_f32_32x32x16_bf16(a1, qf[kf + 1], st1, 0, 0, 0);
    }
    f32x16 st = st0 + st1;

    // online softmax (lane-local q-row = l&31)
    float tmax = st[0];
    #pragma unroll
    for (int r = 1; r < 16; ++r) tmax = fmaxf(tmax, st[r]);
    tmax = fmaxf(tmax, __shfl_xor(tmax, 32, 64));
    float mnew = fmaxf(m, tmax);
    float corr = __expf(m - mnew);
    float p[16];
    float psum = 0.f;
    #pragma unroll
    for (int r = 0; r < 16; ++r) { p[r] = __expf(st[r] - mnew); psum += p[r]; }
    psum += __shfl_xor(psum, 32, 64);
    lsum = lsum * corr + psum;
    m = mnew;
    #pragma unroll
    for (int db = 0; db < 8; ++db) ot[db] *= corr;

    // P -> per-wave LDS tile [32 q][32 kv]
    #pragma unroll
    for (int rp = 0; rp < 4; ++rp) {
      unsigned long long pk = (unsigned long long)f2bf(p[rp * 4]) |
                              ((unsigned long long)f2bf(p[rp * 4 + 1]) << 16) |
                              ((unsigned long long)f2bf(p[rp * 4 + 2]) << 32) |
                              ((unsigned long long)f2bf(p[rp * 4 + 3]) << 48);
      *(unsigned long long*)&P_lds[w][lane31][rp * 8 + grp * 4] = pk;
    }

    // O^T += V^T * P^T (V-frags coalesced from packed layout)
    const short* vbase = VP + ((size_t)(b * 64 + T) * 2) * 4096 + l * 8;
    #pragma unroll
    for (int kf2 = 0; kf2 < 2; ++kf2) {
      short8 pb = *(const short8*)&P_lds[w][lane31][kf2 * 16 + grp * 8];
      #pragma unroll
      for (int db = 0; db < 8; ++db) {
        short8 vf = *(const short8*)(vbase + (size_t)(kf2 * 8 + db) * 512);
        ot[db] = __builtin_amdgcn_mfma_f32_32x32x16_bf16(vf, pb, ot[db], 0, 0, 0);
      }
    }
  }

  // cross-wave merge (4 KV-stripe partials per q-row)
  if (l < 32) { m_sh[w][lane31] = m; l_sh[w][lane31] = lsum; }
  __syncthreads();
  if (t < 128) {
    int c = t >> 5, q = t & 31;
    float ms = fmaxf(fmaxf(m_sh[0][q], m_sh[1][q]), fmaxf(m_sh[2][q], m_sh[3][q]));
    float L = 0.f;
    #pragma unroll
    for (int i = 0; i < 4; ++i) L += l_sh[i][q] * __expf(m_sh[i][q] - ms);
    a_sh[c][q] = __expf(m_sh[c][q] - ms) / L;
  }
  #pragma unroll
  for (int db = 0; db < 8; ++db) {
    __syncthreads();
    #pragma unroll
    for (int r = 0; r < 16; ++r)
      ot_sh[w][(r & 3) + 8 * (r >> 2) + 4 * grp][lane31] = ot[db][r];
    __syncthreads();
    int dloc = t & 31, qq = t >> 5;
    #pragma unroll
    for (int qi = 0; qi < 4; ++qi) {
      int q = qq + 8 * qi;
      float val = a_sh[0][q] * ot_sh[0][dloc][q] + a_sh[1][q] * ot_sh[1][dloc][q] +
                  a_sh[2][q] * ot_sh[2][dloc][q] + a_sh[3][q] * ot_sh[3][dloc][q];
      O[(bS + q0 + q) * 256 + db * 32 + dloc] = val;
    }
  }
}

extern "C" void kernel_launch(void* const* d_in, const int* in_sizes, int n_in,
                              void* d_out, int out_size, void* d_ws, size_t ws_size,
                              hipStream_t stream) {
  (void)in_sizes; (void)n_in; (void)out_size; (void)ws_size;
  const float* query  = (const float*)d_in[0];
  const float* key_in = (const float*)d_in[1];
  const float* value  = (const float*)d_in[2];
  const float* Wq     = (const float*)d_in[3];
  const float* Wk     = (const float*)d_in[4];
  const float* Wv     = (const float*)d_in[5];
  float* out = (float*)d_out;

  short* q_ws = (short*)d_ws;                 // packed Q frags, 8 MB
  short* k_ws = q_ws + (size_t)16384 * 256;   // packed K frags, 8 MB
  short* v_ws = k_ws + (size_t)16384 * 256;   // packed V frags, 8 MB

  dim3 gqk(128, 2), gv(2, 128), ga(64, 8);
  proj_kernel<0><<<gqk, 256, 0, stream>>>(query,  Wq,    q_ws);
  proj_kernel<0><<<gqk, 256, 0, stream>>>(key_in, Wk,    k_ws);
  proj_kernel<1><<<gv,  256, 0, stream>>>(Wv,     value, v_ws);
  attn_kernel<<<ga, 256, 0, stream>>>(q_ws, k_ws, v_ws, out);
}

// Round 4
// 134.565 us; speedup vs baseline: 1.3545x; 1.2419x over previous
//
#include <hip/hip_runtime.h>
#include <hip/hip_bf16.h>

typedef short short8 __attribute__((ext_vector_type(8)));
typedef _Float16 half8 __attribute__((ext_vector_type(8)));
typedef float f32x4  __attribute__((ext_vector_type(4)));
typedef float f32x16 __attribute__((ext_vector_type(16)));
typedef unsigned uint4v __attribute__((ext_vector_type(4)));

__device__ __forceinline__ unsigned short f2h(float f) {
  _Float16 h = (_Float16)f;   // v_cvt_f16_f32, RNE
  return __builtin_bit_cast(unsigned short, h);
}
__device__ __forceinline__ half8 as_h8(short8 s) { return __builtin_bit_cast(half8, s); }

// Fused QKV projection. C = A·B^T in fp16, written in MFMA-fragment-packed order.
// blockIdx.y selects {Q, K, V}. blockIdx.x is XCD-swizzled: batch = x&7 so each
// batch's packed tiles are produced (and stay) in that XCD's L2.
__global__ __launch_bounds__(256) void proj_kernel(
    const float* __restrict__ Aq, const float* __restrict__ Bq,
    const float* __restrict__ Ak, const float* __restrict__ Bk,
    const float* __restrict__ Av, const float* __restrict__ Bv,
    short* __restrict__ Cq, short* __restrict__ Ck, short* __restrict__ Cv) {
  __shared__ short At[128][40];
  __shared__ short Bt[128][40];
  const int y = blockIdx.y;
  const float* A  = (y == 0) ? Aq : (y == 1) ? Ak : Av;
  const float* Bm = (y == 0) ? Bq : (y == 1) ? Bk : Bv;
  short* C        = (y == 0) ? Cq : (y == 1) ? Ck : Cv;
  const int mode = (y == 2);
  const float scale = (y == 0) ? 1.44269504f : 1.0f;  // fold log2e into Q
  const int x = blockIdx.x;
  const int batch = x & 7, loc = (x >> 3) & 15, half = x >> 7;
  int m0, n0;
  if (!mode) { m0 = (batch * 16 + loc) * 128; n0 = half * 128; }
  else       { m0 = half * 128; n0 = (batch * 16 + loc) * 128; }

  const int t = threadIdx.x;
  const int w = t >> 6, l = t & 63;
  const int wr = (w >> 1) * 64, wc = (w & 1) * 64;
  f32x4 acc[4][4] = {};
  for (int k0 = 0; k0 < 256; k0 += 32) {
    __syncthreads();
    #pragma unroll
    for (int rep = 0; rep < 4; ++rep) {
      int row = (t >> 3) + rep * 32;
      int c4  = (t & 7) * 4;
      float4 va = *(const float4*)(A + (size_t)(m0 + row) * 256 + k0 + c4);
      unsigned long long pa = (unsigned long long)f2h(va.x) |
                              ((unsigned long long)f2h(va.y) << 16) |
                              ((unsigned long long)f2h(va.z) << 32) |
                              ((unsigned long long)f2h(va.w) << 48);
      *(unsigned long long*)&At[row][c4] = pa;
      float4 vb = *(const float4*)(Bm + (size_t)(n0 + row) * 256 + k0 + c4);
      unsigned long long pb = (unsigned long long)f2h(vb.x) |
                              ((unsigned long long)f2h(vb.y) << 16) |
                              ((unsigned long long)f2h(vb.z) << 32) |
                              ((unsigned long long)f2h(vb.w) << 48);
      *(unsigned long long*)&Bt[row][c4] = pb;
    }
    __syncthreads();
    short8 af[4], bf[4];
    #pragma unroll
    for (int i = 0; i < 4; ++i) {
      af[i] = *(const short8*)&At[wr + i * 16 + (l & 15)][(l >> 4) * 8];
      bf[i] = *(const short8*)&Bt[wc + i * 16 + (l & 15)][(l >> 4) * 8];
    }
    #pragma unroll
    for (int i = 0; i < 4; ++i)
      #pragma unroll
      for (int j = 0; j < 4; ++j)
        acc[i][j] = __builtin_amdgcn_mfma_f32_16x16x32_f16(as_h8(af[i]), as_h8(bf[j]),
                                                           acc[i][j], 0, 0, 0);
  }
  #pragma unroll
  for (int i = 0; i < 4; ++i)
    #pragma unroll
    for (int j = 0; j < 4; ++j)
      #pragma unroll
      for (int r = 0; r < 4; ++r) {
        int row = m0 + wr + i * 16 + (l >> 4) * 4 + r;
        int col = n0 + wc + j * 16 + (l & 15);
        size_t idx;
        if (!mode) {
          int b = row >> 11, s = row & 2047;
          int T = s >> 5, ln = s & 31;
          int kf = col >> 4, g = (col >> 3) & 1, jj = col & 7;
          idx = (((size_t)(b * 64 + T) * 16 + kf) * 64 + g * 32 + ln) * 8 + jj;
        } else {
          int b = col >> 11, s = col & 2047;
          int T = s >> 5, k2 = (s >> 4) & 1, g = (s >> 3) & 1, jj = s & 7;
          int db = row >> 5, ln = row & 31;
          idx = ((((size_t)(b * 64 + T) * 2 + k2) * 8 + db) * 64 + g * 32 + ln) * 8 + jj;
        }
        C[idx] = (short)f2h(acc[i][j][r] * scale);
      }
}

// Flash attention on fragment-packed fp16 Q/K/V (Q pre-scaled by log2e; exp2
// softmax). 1-D grid 512, XCD-swizzled: batch = bid&7 -> each batch's 3 MB of
// packed QKV lives in one XCD's L2. 4 waves/block, KV split 4-way, in-block merge.
__global__ __launch_bounds__(256, 2) void attn_kernel(const short* __restrict__ QP,
                                                      const short* __restrict__ KP,
                                                      const short* __restrict__ VP,
                                                      float* __restrict__ O) {
  __shared__ float m_sh[4][32], l_sh[4][32], a_sh[4][32];
  __shared__ float ot_sh[4][32][33];
  const int t = threadIdx.x;
  const int w = t >> 6, l = t & 63;
  const int lane31 = l & 31, grp = l >> 5;
  const int bid = blockIdx.x;
  const int b = bid & 7;
  const int q0 = (bid >> 3) * 32;
  const size_t bS = (size_t)b * 2048;

  short8 qf[16];
  const short* qbase = QP + ((size_t)(b * 64 + (q0 >> 5)) * 16) * 512 + l * 8;
  #pragma unroll
  for (int kf = 0; kf < 16; ++kf) qf[kf] = *(const short8*)(qbase + kf * 512);

  f32x16 ot[8] = {};
  float m = -1e30f, lsum = 0.f;

  for (int it = 0; it < 16; ++it) {
    const int T = w + it * 4;
    f32x16 st0 = {}, st1 = {};
    const short* kbase = KP + ((size_t)(b * 64 + T) * 16) * 512 + l * 8;
    #pragma unroll
    for (int kf = 0; kf < 16; kf += 2) {
      short8 a0 = *(const short8*)(kbase + kf * 512);
      short8 a1 = *(const short8*)(kbase + kf * 512 + 512);
      st0 = __builtin_amdgcn_mfma_f32_32x32x16_f16(as_h8(a0), as_h8(qf[kf]), st0, 0, 0, 0);
      st1 = __builtin_amdgcn_mfma_f32_32x32x16_f16(as_h8(a1), as_h8(qf[kf + 1]), st1, 0, 0, 0);
    }
    f32x16 st = st0 + st1;

    // tree max over 16 regs + cross-half
    float a0m = fmaxf(fmaxf(st[0], st[1]), fmaxf(st[2], st[3]));
    float a1m = fmaxf(fmaxf(st[4], st[5]), fmaxf(st[6], st[7]));
    float a2m = fmaxf(fmaxf(st[8], st[9]), fmaxf(st[10], st[11]));
    float a3m = fmaxf(fmaxf(st[12], st[13]), fmaxf(st[14], st[15]));
    float tmax = fmaxf(fmaxf(a0m, a1m), fmaxf(a2m, a3m));
    tmax = fmaxf(tmax, __shfl_xor(tmax, 32, 64));

    // deferred rescale (log2 units; bound 2^11.54 = e^8, well inside fp16 range)
    if (!__all(tmax - m <= 11.544f)) {
      float mnew = fmaxf(m, tmax);
      float corr = exp2f(m - mnew);
      lsum *= corr;
      #pragma unroll
      for (int db = 0; db < 8; ++db) ot[db] *= corr;
      m = mnew;
    }

    float p[16];
    #pragma unroll
    for (int r = 0; r < 16; ++r) p[r] = exp2f(st[r] - m);
    float s0 = (p[0] + p[1]) + (p[2] + p[3]);
    float s1 = (p[4] + p[5]) + (p[6] + p[7]);
    float s2 = (p[8] + p[9]) + (p[10] + p[11]);
    float s3 = (p[12] + p[13]) + (p[14] + p[15]);
    float psum = (s0 + s1) + (s2 + s3);
    psum += __shfl_xor(psum, 32, 64);
    lsum += psum;

    // pack P to fp16 pairs; build PV B-frags in-register via one cross-half
    // exchange per word pair (no LDS round-trip).
    unsigned c[8];
    #pragma unroll
    for (int i = 0; i < 8; ++i) {
      unsigned lo = f2h(p[2 * i]), hi = f2h(p[2 * i + 1]);
      c[i] = lo | (hi << 16);
    }
    const short* vbase = VP + ((size_t)(b * 64 + T) * 2) * 4096 + l * 8;
    #pragma unroll
    for (int kf2 = 0; kf2 < 2; ++kf2) {
      unsigned ca = c[kf2 * 4 + 0], cb = c[kf2 * 4 + 1];
      unsigned cc = c[kf2 * 4 + 2], cd = c[kf2 * 4 + 3];
      unsigned sA = grp ? ca : cc;                       // what my partner needs
      unsigned rA = (unsigned)__shfl_xor((int)sA, 32, 64);
      unsigned sB = grp ? cb : cd;
      unsigned rB = (unsigned)__shfl_xor((int)sB, 32, 64);
      uint4v pw;
      pw[0] = grp ? rA : ca;   // k = grp*8 + {0,1}
      pw[1] = grp ? rB : cb;   // k = grp*8 + {2,3}
      pw[2] = grp ? cc : rA;   // k = grp*8 + {4,5}
      pw[3] = grp ? cd : rB;   // k = grp*8 + {6,7}
      half8 pb = __builtin_bit_cast(half8, pw);
      #pragma unroll
      for (int db = 0; db < 8; ++db) {
        short8 vf = *(const short8*)(vbase + (size_t)(kf2 * 8 + db) * 512);
        ot[db] = __builtin_amdgcn_mfma_f32_32x32x16_f16(as_h8(vf), pb, ot[db], 0, 0, 0);
      }
    }
  }

  // cross-wave merge (4 KV-stripe partials per q-row)
  if (l < 32) { m_sh[w][lane31] = m; l_sh[w][lane31] = lsum; }
  __syncthreads();
  if (t < 128) {
    int c2 = t >> 5, q = t & 31;
    float ms = fmaxf(fmaxf(m_sh[0][q], m_sh[1][q]), fmaxf(m_sh[2][q], m_sh[3][q]));
    float L = 0.f;
    #pragma unroll
    for (int i = 0; i < 4; ++i) L += l_sh[i][q] * exp2f(m_sh[i][q] - ms);
    a_sh[c2][q] = exp2f(m_sh[c2][q] - ms) / L;
  }
  #pragma unroll
  for (int db = 0; db < 8; ++db) {
    __syncthreads();
    #pragma unroll
    for (int r = 0; r < 16; ++r)
      ot_sh[w][(r & 3) + 8 * (r >> 2) + 4 * grp][lane31] = ot[db][r];
    __syncthreads();
    int dloc = t & 31, qq = t >> 5;
    #pragma unroll
    for (int qi = 0; qi < 4; ++qi) {
      int q = qq + 8 * qi;
      float val = a_sh[0][q] * ot_sh[0][dloc][q] + a_sh[1][q] * ot_sh[1][dloc][q] +
                  a_sh[2][q] * ot_sh[2][dloc][q] + a_sh[3][q] * ot_sh[3][dloc][q];
      O[(bS + q0 + q) * 256 + db * 32 + dloc] = val;
    }
  }
}

extern "C" void kernel_launch(void* const* d_in, const int* in_sizes, int n_in,
                              void* d_out, int out_size, void* d_ws, size_t ws_size,
                              hipStream_t stream) {
  (void)in_sizes; (void)n_in; (void)out_size; (void)ws_size;
  const float* query  = (const float*)d_in[0];
  const float* key_in = (const float*)d_in[1];
  const float* value  = (const float*)d_in[2];
  const float* Wq     = (const float*)d_in[3];
  const float* Wk     = (const float*)d_in[4];
  const float* Wv     = (const float*)d_in[5];
  float* out = (float*)d_out;

  short* q_ws = (short*)d_ws;                 // packed Q frags fp16 (pre-scaled by log2e), 8 MB
  short* k_ws = q_ws + (size_t)16384 * 256;   // packed K frags fp16, 8 MB
  short* v_ws = k_ws + (size_t)16384 * 256;   // packed V frags fp16, 8 MB

  dim3 gp(256, 3), ga(512);
  proj_kernel<<<gp, 256, 0, stream>>>(query, Wq, key_in, Wk, Wv, value,
                                      q_ws, k_ws, v_ws);
  attn_kernel<<<ga, 256, 0, stream>>>(q_ws, k_ws, v_ws, out);
}

// Round 5
// 81.591 us; speedup vs baseline: 2.2339x; 1.6493x over previous
//
#include <hip/hip_runtime.h>
#include <hip/hip_bf16.h>

typedef short short8 __attribute__((ext_vector_type(8)));
typedef _Float16 half8 __attribute__((ext_vector_type(8)));
typedef float f32x4  __attribute__((ext_vector_type(4)));
typedef float f32x16 __attribute__((ext_vector_type(16)));

__device__ __forceinline__ unsigned short f2h(float f) {
  _Float16 h = (_Float16)f;   // v_cvt_f16_f32, RNE
  return __builtin_bit_cast(unsigned short, h);
}
__device__ __forceinline__ half8 as_h8(short8 s) { return __builtin_bit_cast(half8, s); }

// Fused QKV projection. C = A·B^T in fp16, written in MFMA-fragment-packed order.
// blockIdx.y selects {Q, K, V}. blockIdx.x is XCD-swizzled: batch = x&7 so each
// batch's packed tiles are produced (and stay) in that XCD's L2.
__global__ __launch_bounds__(256) void proj_kernel(
    const float* __restrict__ Aq, const float* __restrict__ Bq,
    const float* __restrict__ Ak, const float* __restrict__ Bk,
    const float* __restrict__ Av, const float* __restrict__ Bv,
    short* __restrict__ Cq, short* __restrict__ Ck, short* __restrict__ Cv) {
  __shared__ short At[128][40];
  __shared__ short Bt[128][40];
  const int y = blockIdx.y;
  const float* A  = (y == 0) ? Aq : (y == 1) ? Ak : Av;
  const float* Bm = (y == 0) ? Bq : (y == 1) ? Bk : Bv;
  short* C        = (y == 0) ? Cq : (y == 1) ? Ck : Cv;
  const int mode = (y == 2);
  const float scale = (y == 0) ? 1.44269504f : 1.0f;  // fold log2e into Q
  const int x = blockIdx.x;
  const int batch = x & 7, loc = (x >> 3) & 15, half = x >> 7;
  int m0, n0;
  if (!mode) { m0 = (batch * 16 + loc) * 128; n0 = half * 128; }
  else       { m0 = half * 128; n0 = (batch * 16 + loc) * 128; }

  const int t = threadIdx.x;
  const int w = t >> 6, l = t & 63;
  const int wr = (w >> 1) * 64, wc = (w & 1) * 64;
  f32x4 acc[4][4] = {};
  for (int k0 = 0; k0 < 256; k0 += 32) {
    __syncthreads();
    #pragma unroll
    for (int rep = 0; rep < 4; ++rep) {
      int row = (t >> 3) + rep * 32;
      int c4  = (t & 7) * 4;
      float4 va = *(const float4*)(A + (size_t)(m0 + row) * 256 + k0 + c4);
      unsigned long long pa = (unsigned long long)f2h(va.x) |
                              ((unsigned long long)f2h(va.y) << 16) |
                              ((unsigned long long)f2h(va.z) << 32) |
                              ((unsigned long long)f2h(va.w) << 48);
      *(unsigned long long*)&At[row][c4] = pa;
      float4 vb = *(const float4*)(Bm + (size_t)(n0 + row) * 256 + k0 + c4);
      unsigned long long pb = (unsigned long long)f2h(vb.x) |
                              ((unsigned long long)f2h(vb.y) << 16) |
                              ((unsigned long long)f2h(vb.z) << 32) |
                              ((unsigned long long)f2h(vb.w) << 48);
      *(unsigned long long*)&Bt[row][c4] = pb;
    }
    __syncthreads();
    short8 af[4], bf[4];
    #pragma unroll
    for (int i = 0; i < 4; ++i) {
      af[i] = *(const short8*)&At[wr + i * 16 + (l & 15)][(l >> 4) * 8];
      bf[i] = *(const short8*)&Bt[wc + i * 16 + (l & 15)][(l >> 4) * 8];
    }
    #pragma unroll
    for (int i = 0; i < 4; ++i)
      #pragma unroll
      for (int j = 0; j < 4; ++j)
        acc[i][j] = __builtin_amdgcn_mfma_f32_16x16x32_f16(as_h8(af[i]), as_h8(bf[j]),
                                                           acc[i][j], 0, 0, 0);
  }
  #pragma unroll
  for (int i = 0; i < 4; ++i)
    #pragma unroll
    for (int j = 0; j < 4; ++j)
      #pragma unroll
      for (int r = 0; r < 4; ++r) {
        int row = m0 + wr + i * 16 + (l >> 4) * 4 + r;
        int col = n0 + wc + j * 16 + (l & 15);
        size_t idx;
        if (!mode) {
          int b = row >> 11, s = row & 2047;
          int T = s >> 5, ln = s & 31;
          int kf = col >> 4, g = (col >> 3) & 1, jj = col & 7;
          idx = (((size_t)(b * 64 + T) * 16 + kf) * 64 + g * 32 + ln) * 8 + jj;
        } else {
          int b = col >> 11, s = col & 2047;
          int T = s >> 5, k2 = (s >> 4) & 1, g = (s >> 3) & 1, jj = s & 7;
          int db = row >> 5, ln = row & 31;
          idx = ((((size_t)(b * 64 + T) * 2 + k2) * 8 + db) * 64 + g * 32 + ln) * 8 + jj;
        }
        C[idx] = (short)f2h(acc[i][j][r] * scale);
      }
}

// Flash attention, 512-thread blocks (8 waves). Per block: 32 q-rows.
// QK/softmax: wave w owns KV tile it*8+w (8 iterations x 8 tiles).
// Block-global running max via LDS reduce each iteration -> P tiles share scale.
// PV: wave w owns d-slice [w*32, w*32+32), consumes all 8 P tiles from LDS.
// Accumulator = 32 regs/wave -> 4 waves/SIMD occupancy target.
__global__ __launch_bounds__(512, 4) void attn_kernel(const short* __restrict__ QP,
                                                      const short* __restrict__ KP,
                                                      const short* __restrict__ VP,
                                                      float* __restrict__ O) {
  __shared__ short Qlds[16 * 512];       // packed Q frags, 16 KB
  __shared__ short Plds[8][32][40];      // 8 P tiles [q][kv], 20 KB
  __shared__ float mx_sh[32][8];
  __shared__ float l_sh[32][8];
  __shared__ float tbuf[8][32][33];      // per-wave transpose buffers

  const int t = threadIdx.x;
  const int w = t >> 6, l = t & 63;
  const int lane31 = l & 31, grp = l >> 5;
  const int bid = blockIdx.x;
  const int b = bid & 7;                 // XCD-local batch
  const int q0 = (bid >> 3) * 32;
  const size_t bS = (size_t)b * 2048;

  // stage this q-tile's packed Q frags into LDS (shared by all 8 waves)
  {
    const short* qsrc = QP + ((size_t)(b * 64 + (q0 >> 5)) * 16) * 512;
    *(short8*)&Qlds[t * 8] = *(const short8*)(qsrc + t * 8);
    *(short8*)&Qlds[(t + 512) * 8] = *(const short8*)(qsrc + (t + 512) * 8);
  }
  __syncthreads();

  f32x16 ot0 = {}, ot1 = {};
  float m = -1e30f, lsum = 0.f;

  for (int it = 0; it < 8; ++it) {
    const int T = it * 8 + w;
    // S^T = K * Q^T for tile T (two interleaved chains)
    f32x16 st0 = {}, st1 = {};
    const short* kbase = KP + ((size_t)(b * 64 + T) * 16) * 512 + l * 8;
    #pragma unroll
    for (int kf = 0; kf < 16; kf += 2) {
      short8 a0 = *(const short8*)(kbase + kf * 512);
      short8 a1 = *(const short8*)(kbase + (kf + 1) * 512);
      short8 qa = *(const short8*)&Qlds[kf * 512 + l * 8];
      short8 qb = *(const short8*)&Qlds[(kf + 1) * 512 + l * 8];
      st0 = __builtin_amdgcn_mfma_f32_32x32x16_f16(as_h8(a0), as_h8(qa), st0, 0, 0, 0);
      st1 = __builtin_amdgcn_mfma_f32_32x32x16_f16(as_h8(a1), as_h8(qb), st1, 0, 0, 0);
    }
    f32x16 st = st0 + st1;

    // per-wave tile max -> LDS -> block max (per q-row)
    float a0m = fmaxf(fmaxf(st[0], st[1]), fmaxf(st[2], st[3]));
    float a1m = fmaxf(fmaxf(st[4], st[5]), fmaxf(st[6], st[7]));
    float a2m = fmaxf(fmaxf(st[8], st[9]), fmaxf(st[10], st[11]));
    float a3m = fmaxf(fmaxf(st[12], st[13]), fmaxf(st[14], st[15]));
    float tmax = fmaxf(fmaxf(a0m, a1m), fmaxf(a2m, a3m));
    tmax = fmaxf(tmax, __shfl_xor(tmax, 32, 64));
    if (l < 32) mx_sh[lane31][w] = tmax;
    __syncthreads();  // A: mx visible; prior iteration's P reads complete
    f32x4 mA = *(const f32x4*)&mx_sh[lane31][0];
    f32x4 mB = *(const f32x4*)&mx_sh[lane31][4];
    float t8 = fmaxf(fmaxf(fmaxf(mA[0], mA[1]), fmaxf(mA[2], mA[3])),
                     fmaxf(fmaxf(mB[0], mB[1]), fmaxf(mB[2], mB[3])));

    // deferred rescale; condition identical in every wave (same t8, same m)
    if (!__all(t8 - m <= 11.544f)) {
      float mnew = fmaxf(m, t8);
      float corr = exp2f(m - mnew);
      lsum *= corr;
      ot0 *= corr;
      ot1 *= corr;
      m = mnew;
    }

    float p[16];
    #pragma unroll
    for (int r = 0; r < 16; ++r) p[r] = exp2f(st[r] - m);
    float s0 = (p[0] + p[1]) + (p[2] + p[3]);
    float s1 = (p[4] + p[5]) + (p[6] + p[7]);
    float s2 = (p[8] + p[9]) + (p[10] + p[11]);
    float s3 = (p[12] + p[13]) + (p[14] + p[15]);
    float psum = (s0 + s1) + (s2 + s3);
    psum += __shfl_xor(psum, 32, 64);
    lsum += psum;

    // pack P pairs -> LDS tile [q][kv] (stride 40 shorts, 16B-aligned rows)
    #pragma unroll
    for (int i = 0; i < 8; ++i) {
      unsigned cw = (unsigned)f2h(p[2 * i]) | ((unsigned)f2h(p[2 * i + 1]) << 16);
      int kvb = ((2 * i) & 3) + 8 * (i >> 1) + 4 * grp;
      *(unsigned*)&Plds[w][lane31][kvb] = cw;
    }
    __syncthreads();  // B: P tiles visible

    // PV: wave w's d-slice over all 8 tiles; kf2 0->ot0, 1->ot1 (2 chains)
    #pragma unroll
    for (int t2 = 0; t2 < 8; ++t2) {
      const size_t T2 = (size_t)(b * 64 + it * 8 + t2) * 16 + w;
      short8 pb0 = *(const short8*)&Plds[t2][lane31][grp * 8];
      short8 pb1 = *(const short8*)&Plds[t2][lane31][16 + grp * 8];
      short8 vf0 = *(const short8*)(VP + T2 * 512 + l * 8);
      short8 vf1 = *(const short8*)(VP + (T2 + 8) * 512 + l * 8);
      ot0 = __builtin_amdgcn_mfma_f32_32x32x16_f16(as_h8(vf0), as_h8(pb0), ot0, 0, 0, 0);
      ot1 = __builtin_amdgcn_mfma_f32_32x32x16_f16(as_h8(vf1), as_h8(pb1), ot1, 0, 0, 0);
    }
  }

  // block lsum = sum of 8 per-wave partials (common m)
  if (l < 32) l_sh[lane31][w] = lsum;
  __syncthreads();
  f32x4 lA = *(const f32x4*)&l_sh[lane31][0];
  f32x4 lB = *(const f32x4*)&l_sh[lane31][4];
  float Ltot = ((lA[0] + lA[1]) + (lA[2] + lA[3])) + ((lB[0] + lB[1]) + (lB[2] + lB[3]));
  float invL = 1.0f / Ltot;

  // scale in-register, transpose via per-wave LDS buffer, coalesced store
  #pragma unroll
  for (int r = 0; r < 16; ++r)
    tbuf[w][(r & 3) + 8 * (r >> 2) + 4 * grp][lane31] = (ot0[r] + ot1[r]) * invL;
  #pragma unroll
  for (int rr = 0; rr < 16; ++rr) {
    int q = grp + rr * 2;
    O[(bS + q0 + q) * 256 + w * 32 + lane31] = tbuf[w][lane31][q];
  }
}

extern "C" void kernel_launch(void* const* d_in, const int* in_sizes, int n_in,
                              void* d_out, int out_size, void* d_ws, size_t ws_size,
                              hipStream_t stream) {
  (void)in_sizes; (void)n_in; (void)out_size; (void)ws_size;
  const float* query  = (const float*)d_in[0];
  const float* key_in = (const float*)d_in[1];
  const float* value  = (const float*)d_in[2];
  const float* Wq     = (const float*)d_in[3];
  const float* Wk     = (const float*)d_in[4];
  const float* Wv     = (const float*)d_in[5];
  float* out = (float*)d_out;

  short* q_ws = (short*)d_ws;                 // packed Q frags fp16 (pre-scaled by log2e), 8 MB
  short* k_ws = q_ws + (size_t)16384 * 256;   // packed K frags fp16, 8 MB
  short* v_ws = k_ws + (size_t)16384 * 256;   // packed V frags fp16, 8 MB

  dim3 gp(256, 3), ga(512);
  proj_kernel<<<gp, 256, 0, stream>>>(query, Wq, key_in, Wk, Wv, value,
                                      q_ws, k_ws, v_ws);
  attn_kernel<<<ga, 512, 0, stream>>>(q_ws, k_ws, v_ws, out);
}